// Round 1
// baseline (556.115 us; speedup 1.0000x reference)
//
#include <hip/hip_runtime.h>
#include <stdint.h>

typedef __attribute__((ext_vector_type(8))) short bf16x8;   // 8 bf16 in 4 VGPRs
typedef __attribute__((ext_vector_type(4))) float f32x4;
typedef __attribute__((ext_vector_type(4))) unsigned short us4;
typedef unsigned short ushort;
typedef unsigned int uint;

#define MFMA16(a,b,c) __builtin_amdgcn_mfma_f32_16x16x32_bf16((a),(b),(c),0,0,0)

__device__ __forceinline__ ushort f2bf(float f){
  uint u = __builtin_bit_cast(uint, f);
  return (ushort)((u + 0x7fffu + ((u>>16)&1u)) >> 16);   // RTNE
}
__device__ __forceinline__ float bf2f(ushort h){
  return __builtin_bit_cast(float, ((uint)h)<<16);
}
__device__ __forceinline__ void gll16(const void* g, void* l){
  // async global->LDS, 16B per lane; LDS dest must be wave-uniform base (HW adds lane*16)
  __builtin_amdgcn_global_load_lds((const __attribute__((address_space(1))) void*)g,
                                   (__attribute__((address_space(3))) void*)l, 16, 0, 0);
}

// ---------------- generic 128x128 GEMM core (A row-major [.,K], B^T row-major [N,K], bf16) ---
// SPLIT: C = Ah*Bh + Ah*Bl + Al*Bh  (split-precision bf16 hi/lo)
template<bool SPLIT, int BK>
__device__ __forceinline__ void gemm_core(
    const char* __restrict__ Ah, const char* __restrict__ Al,
    const char* __restrict__ Bh, const char* __restrict__ Bl,
    int K, int lda, int ldb, int m0, int n0,
    f32x4 acc[4][4], char* sAh, char* sAl, char* sBh, char* sBl)
{
  constexpr int ROWB = BK*2;               // bytes per LDS row
  constexpr int CHUNKS = 128*ROWB/1024;    // 1KB wave-chunks per tile
  constexpr int XM = ((ROWB/16)-1) & 7;    // XOR-swizzle mask (16B granules per row)
  const int tid = threadIdx.x;
  const int wave = tid>>6, lane = tid&63;
  const int l15 = lane&15, l4 = lane>>4;
  const int wr = (wave>>1)*64, wc = (wave&1)*64;
  const int nsteps = K / BK;
  for (int kt = 0; kt < nsteps; ++kt) {
    const int kb0 = kt*ROWB;
    for (int c = wave; c < CHUNKS; c += 4) {
      const int p = (c<<10) + (lane<<4);
      const int row = p / ROWB;
      const int gk = (p % ROWB) ^ ((row & XM)<<4);   // pre-swizzled global source
      gll16(Ah + (size_t)(m0+row)*lda + kb0 + gk, sAh + (c<<10));
      gll16(Bh + (size_t)(n0+row)*ldb + kb0 + gk, sBh + (c<<10));
      if constexpr (SPLIT) {
        gll16(Al + (size_t)(m0+row)*lda + kb0 + gk, sAl + (c<<10));
        gll16(Bl + (size_t)(n0+row)*ldb + kb0 + gk, sBl + (c<<10));
      }
    }
    __syncthreads();
    #pragma unroll
    for (int ks = 0; ks < BK/32; ++ks) {
      bf16x8 ah[4], bh_[4], al[4], bl[4];
      #pragma unroll
      for (int i = 0; i < 4; ++i) {
        const int ar = wr + i*16 + l15;
        const int ao = ar*ROWB + ((ks*64 + l4*16) ^ ((ar & XM)<<4));
        ah[i] = *(const bf16x8*)(sAh + ao);
        const int br = wc + i*16 + l15;
        const int bo = br*ROWB + ((ks*64 + l4*16) ^ ((br & XM)<<4));
        bh_[i] = *(const bf16x8*)(sBh + bo);
        if constexpr (SPLIT) {
          al[i] = *(const bf16x8*)(sAl + ao);
          bl[i] = *(const bf16x8*)(sBl + bo);
        }
      }
      #pragma unroll
      for (int mi = 0; mi < 4; ++mi) {
        #pragma unroll
        for (int ni = 0; ni < 4; ++ni) {
          acc[mi][ni] = MFMA16(ah[mi], bh_[ni], acc[mi][ni]);
          if constexpr (SPLIT) {
            acc[mi][ni] = MFMA16(ah[mi], bl[ni], acc[mi][ni]);
            acc[mi][ni] = MFMA16(al[mi], bh_[ni], acc[mi][ni]);
          }
        }
      }
    }
    __syncthreads();
  }
}

// ---------------- weight prep: split WQ/WK into bf16 hi/lo, convert WV/W_O -------------------
__global__ __launch_bounds__(256) void k_prep(
    const float* __restrict__ wq, const float* __restrict__ wk,
    const float* __restrict__ wv, const float* __restrict__ wo,
    ushort* qh, ushort* ql_, ushort* kh, ushort* kl_, ushort* vb, ushort* ob)
{
  int i = blockIdx.x*256 + threadIdx.x;
  if (i >= 589824) return;
  float a = wq[i]; ushort h = f2bf(a); qh[i]=h; ql_[i]=f2bf(a - bf2f(h));
  float b = wk[i]; h = f2bf(b); kh[i]=h; kl_[i]=f2bf(b - bf2f(h));
  vb[i] = f2bf(wv[i]); ob[i] = f2bf(wo[i]);
}

// ---------------- fp32 [R][C] -> bf16 [C][R] transpose --------------------------------------
__global__ __launch_bounds__(256) void k_transpose(
    const float* __restrict__ in, ushort* __restrict__ out, int R, int C)
{
  __shared__ float t[32][33];
  const int bx = blockIdx.x*32, by = blockIdx.y*32;
  const int tx = threadIdx.x & 31, ty = threadIdx.x >> 5;
  #pragma unroll
  for (int i = 0; i < 4; ++i)
    t[ty + i*8][tx] = in[(size_t)(by + ty + i*8)*C + bx + tx];
  __syncthreads();
  #pragma unroll
  for (int i = 0; i < 4; ++i)
    out[(size_t)(bx + ty + i*8)*R + by + tx] = f2bf(t[tx][ty + i*8]);
}

// ---------------- layernorm over 768, fp32 in -> bf16 hi (+optional lo) ---------------------
__global__ __launch_bounds__(256) void k_ln(
    const float* __restrict__ in, const float* __restrict__ g, const float* __restrict__ be,
    ushort* __restrict__ oh, ushort* __restrict__ ol)
{
  const int row = blockIdx.x, t = threadIdx.x;
  const float* r = in + (size_t)row*768;
  float v0 = r[t], v1 = r[t+256], v2 = r[t+512];
  float s = v0+v1+v2;
  float q = v0*v0 + v1*v1 + v2*v2;
  #pragma unroll
  for (int m = 32; m; m >>= 1) { s += __shfl_xor(s, m); q += __shfl_xor(q, m); }
  __shared__ float ss[4], sq[4];
  const int wave = t>>6, lane = t&63;
  if (!lane) { ss[wave] = s; sq[wave] = q; }
  __syncthreads();
  s = ss[0]+ss[1]+ss[2]+ss[3];
  q = sq[0]+sq[1]+sq[2]+sq[3];
  const float mu = s*(1.f/768.f);
  const float var = q*(1.f/768.f) - mu*mu;
  const float inv = rsqrtf(var + 1e-5f);
  const float vv[3] = {v0, v1, v2};
  #pragma unroll
  for (int i = 0; i < 3; ++i) {
    const int idx = t + i*256;
    const float u = (vv[i]-mu)*inv*g[idx] + be[idx];
    const ushort hi = f2bf(u);
    oh[(size_t)row*768 + idx] = hi;
    if (ol) ol[(size_t)row*768 + idx] = f2bf(u - bf2f(hi));
  }
}

// ---------------- QKV projection: z=0 Q(split), z=1 K(split), z=2 V(plain, writes V^T) ------
__global__ __launch_bounds__(256) void k_qkv(
    const ushort* __restrict__ uh, const ushort* __restrict__ ul,
    const ushort* __restrict__ wqh, const ushort* __restrict__ wql,
    const ushort* __restrict__ wkh, const ushort* __restrict__ wkl,
    const ushort* __restrict__ wvb,
    ushort* __restrict__ Qh, ushort* __restrict__ Ql,
    ushort* __restrict__ Kh, ushort* __restrict__ Kl,
    ushort* __restrict__ Vt)
{
  __shared__ char sA[8192], sA2[8192], sB[8192], sB2[8192];
  const int z = blockIdx.z;
  const int m0 = blockIdx.x*128, n0 = blockIdx.y*128;
  f32x4 acc[4][4] = {};
  if (z == 0)
    gemm_core<true,32>((const char*)uh, (const char*)ul, (const char*)wqh, (const char*)wql,
                       768, 1536, 1536, m0, n0, acc, sA, sA2, sB, sB2);
  else if (z == 1)
    gemm_core<true,32>((const char*)uh, (const char*)ul, (const char*)wkh, (const char*)wkl,
                       768, 1536, 1536, m0, n0, acc, sA, sA2, sB, sB2);
  else
    gemm_core<false,32>((const char*)uh, nullptr, (const char*)wvb, nullptr,
                        768, 1536, 1536, m0, n0, acc, sA, sA2, sB, sB2);

  const int tid = threadIdx.x, wave = tid>>6, lane = tid&63;
  const int l15 = lane&15, l4 = lane>>4;
  const int wr = (wave>>1)*64, wc = (wave&1)*64;
  if (z < 2) {
    ushort* __restrict__ Oh = z ? Kh : Qh;
    ushort* __restrict__ Ol = z ? Kl : Ql;
    #pragma unroll
    for (int mi = 0; mi < 4; ++mi) {
      #pragma unroll
      for (int ni = 0; ni < 4; ++ni) {
        const int he = n0 + wc + ni*16 + l15;
        const int h = he>>6, e = he&63;
        #pragma unroll
        for (int r = 0; r < 4; ++r) {
          const int n = m0 + wr + mi*16 + l4*4 + r;
          const int b = n>>11, l = n&2047;
          const size_t dst = ((size_t)((b*12+h)*2048 + l))*64 + e;
          const float c = acc[mi][ni][r];
          const ushort hi = f2bf(c);
          Oh[dst] = hi;
          Ol[dst] = f2bf(c - bf2f(hi));
        }
      }
    }
  } else {
    #pragma unroll
    for (int mi = 0; mi < 4; ++mi) {
      #pragma unroll
      for (int ni = 0; ni < 4; ++ni) {
        const int he = n0 + wc + ni*16 + l15;
        const int h = he>>6, e = he&63;
        const int n = m0 + wr + mi*16 + l4*4;
        const int b = n>>11, l = n&2047;
        us4 v;
        #pragma unroll
        for (int r = 0; r < 4; ++r) v[r] = f2bf(acc[mi][ni][r]);
        *(us4*)(Vt + ((size_t)((b*12+h)*64 + e))*2048 + l) = v;
      }
    }
  }
}

// ---------------- fused causal attention, tanh-clipped, no-rescale online softmax -----------
// grid (32 qtiles, 24 bh); block 256; BQ=BKV=64; wave w owns q rows w*16..w*16+15
__global__ __launch_bounds__(256) void k_attn(
    const ushort* __restrict__ Qh, const ushort* __restrict__ Ql,
    const ushort* __restrict__ Kh, const ushort* __restrict__ Kl,
    const ushort* __restrict__ Vt, const int* __restrict__ am,
    ushort* __restrict__ Oc)
{
  __shared__ char sKh[8192], sKl[8192], sV[8192];
  __shared__ char sP[4][2048];
  const int qt = gridDim.x - 1 - blockIdx.x;    // big tiles first
  const int bh = blockIdx.y;
  const int b = bh / 12, h = bh - b*12;
  const int tid = threadIdx.x, wave = tid>>6, lane = tid&63;
  const int l15 = lane&15, l4 = lane>>4;

  const size_t qoff = ((size_t)bh*2048 + qt*64 + wave*16 + l15)*64 + l4*8;
  const bf16x8 q_h0 = *(const bf16x8*)(Qh + qoff);
  const bf16x8 q_h1 = *(const bf16x8*)(Qh + qoff + 32);
  const bf16x8 q_l0 = *(const bf16x8*)(Ql + qoff);
  const bf16x8 q_l1 = *(const bf16x8*)(Ql + qoff + 32);

  f32x4 oacc[4] = {};
  float dsum[4] = {0.f, 0.f, 0.f, 0.f};
  const char* Kh_t = (const char*)(Kh + (size_t)bh*2048*64);
  const char* Kl_t = (const char*)(Kl + (size_t)bh*2048*64);
  const char* Vt_b = (const char*)(Vt + (size_t)bh*64*2048);

  for (int kt = 0; kt <= qt; ++kt) {
    // stage K_hi/K_lo [64 key][64 e] and V^T [64 e][64 key] tiles, XOR-swizzled via source
    for (int c = wave; c < 24; c += 4) {
      const int p = ((c&7)<<10) + (lane<<4);
      const int row = p >> 7;
      const int gkb = (p & 127) ^ ((row&7)<<4);
      const char* gsrc; char* lbase;
      if (c < 8)       { gsrc = Kh_t + (size_t)(kt*64+row)*128 + gkb; lbase = sKh + ((c&7)<<10); }
      else if (c < 16) { gsrc = Kl_t + (size_t)(kt*64+row)*128 + gkb; lbase = sKl + ((c&7)<<10); }
      else             { gsrc = Vt_b + (size_t)row*4096 + kt*128 + gkb; lbase = sV + ((c&7)<<10); }
      gll16(gsrc, lbase);
    }
    __syncthreads();

    // S = Q K^T (3-term split product)
    f32x4 s[4] = {};
    #pragma unroll
    for (int ks = 0; ks < 2; ++ks) {
      bf16x8 kbh[4], kbl[4];
      #pragma unroll
      for (int nt = 0; nt < 4; ++nt) {
        const int key = nt*16 + l15;
        const int byte = key*128 + ((ks*64 + l4*16) ^ ((key&7)<<4));
        kbh[nt] = *(const bf16x8*)(sKh + byte);
        kbl[nt] = *(const bf16x8*)(sKl + byte);
      }
      const bf16x8 qh_ = ks ? q_h1 : q_h0;
      const bf16x8 ql_ = ks ? q_l1 : q_l0;
      #pragma unroll
      for (int nt = 0; nt < 4; ++nt) {
        s[nt] = MFMA16(qh_, kbh[nt], s[nt]);
        s[nt] = MFMA16(qh_, kbl[nt], s[nt]);
        s[nt] = MFMA16(ql_, kbh[nt], s[nt]);
      }
    }

    // tanh clip + causal + pad mask + exp(S-30); stash P (bf16) in per-wave LDS
    const bool diag = (kt == qt);
    #pragma unroll
    for (int nt = 0; nt < 4; ++nt) {
      const int key_g = kt*64 + nt*16 + l15;
      const float mv = (float)am[b*2048 + key_g];
      #pragma unroll
      for (int r = 0; r < 4; ++r) {
        const float sv = s[nt][r]*0.125f;
        const float th = 1.f - 2.f/(1.f + __expf(2.f*sv));
        float p = __expf(30.f*th - 30.f) * mv;
        if (diag && key_g > qt*64 + wave*16 + l4*4 + r) p = 0.f;
        dsum[r] += p;
        const int qi = l4*4 + r;
        const int byte = qi*128 + ((nt*32 + l15*2) ^ ((qi&7)<<4));
        *(ushort*)(sP[wave] + byte) = f2bf(p);
      }
    }

    // O += P V
    #pragma unroll
    for (int ks = 0; ks < 2; ++ks) {
      const int abyte = l15*128 + ((ks*64 + l4*16) ^ ((l15&7)<<4));
      const bf16x8 pa = *(const bf16x8*)(sP[wave] + abyte);
      #pragma unroll
      for (int et = 0; et < 4; ++et) {
        const int e_l = et*16 + l15;
        const int vbyte = e_l*128 + ((ks*64 + l4*16) ^ ((e_l&7)<<4));
        const bf16x8 vb = *(const bf16x8*)(sV + vbyte);
        oacc[et] = MFMA16(pa, vb, oacc[et]);
      }
    }
    __syncthreads();
  }

  #pragma unroll
  for (int r = 0; r < 4; ++r) {
    float d = dsum[r];
    d += __shfl_xor(d, 1); d += __shfl_xor(d, 2);
    d += __shfl_xor(d, 4); d += __shfl_xor(d, 8);
    dsum[r] = 1.f/d;
  }
  #pragma unroll
  for (int et = 0; et < 4; ++et) {
    #pragma unroll
    for (int r = 0; r < 4; ++r) {
      const int q_g = qt*64 + wave*16 + l4*4 + r;
      const size_t n = (size_t)b*2048 + q_g;
      const int he = h*64 + et*16 + l15;
      Oc[n*768 + he] = f2bf(oacc[et][r]*dsum[r]);
    }
  }
}

// ---------------- W_O GEMM + residual: z1 = x + O_cat @ W_O^T -------------------------------
__global__ __launch_bounds__(256) void k_wo(
    const ushort* __restrict__ oc, const ushort* __restrict__ wob,
    const float* __restrict__ x, float* __restrict__ z1)
{
  __shared__ char sA[16384], sB[16384];
  const int m0 = blockIdx.x*128, n0 = blockIdx.y*128;
  f32x4 acc[4][4] = {};
  gemm_core<false,64>((const char*)oc, nullptr, (const char*)wob, nullptr,
                      768, 1536, 1536, m0, n0, acc, sA, nullptr, sB, nullptr);
  const int tid = threadIdx.x, wave = tid>>6, lane = tid&63;
  const int l15 = lane&15, l4 = lane>>4;
  const int wr = (wave>>1)*64, wc = (wave&1)*64;
  #pragma unroll
  for (int mi = 0; mi < 4; ++mi) {
    #pragma unroll
    for (int ni = 0; ni < 4; ++ni) {
      const int d = n0 + wc + ni*16 + l15;
      #pragma unroll
      for (int r = 0; r < 4; ++r) {
        const int n = m0 + wr + mi*16 + l4*4 + r;
        z1[(size_t)n*768 + d] = x[(size_t)n*768 + d] + acc[mi][ni][r];
      }
    }
  }
}

// ---------------- MLP up: v3 = gelu(v1 @ W_up + b_up) ---------------------------------------
__global__ __launch_bounds__(256) void k_up(
    const ushort* __restrict__ v1, const ushort* __restrict__ wupT,
    const float* __restrict__ bup, ushort* __restrict__ v3)
{
  __shared__ char sA[16384], sB[16384];
  const int m0 = blockIdx.x*128, n0 = blockIdx.y*128;
  f32x4 acc[4][4] = {};
  gemm_core<false,64>((const char*)v1, nullptr, (const char*)wupT, nullptr,
                      768, 1536, 1536, m0, n0, acc, sA, nullptr, sB, nullptr);
  const int tid = threadIdx.x, wave = tid>>6, lane = tid&63;
  const int l15 = lane&15, l4 = lane>>4;
  const int wr = (wave>>1)*64, wc = (wave&1)*64;
  #pragma unroll
  for (int mi = 0; mi < 4; ++mi) {
    #pragma unroll
    for (int ni = 0; ni < 4; ++ni) {
      const int j = n0 + wc + ni*16 + l15;
      const float bj = bup[j];
      #pragma unroll
      for (int r = 0; r < 4; ++r) {
        const int n = m0 + wr + mi*16 + l4*4 + r;
        const float c = acc[mi][ni][r] + bj;
        const float ge = 0.5f*c*(1.f + erff(c*0.70710678118654752f));
        v3[(size_t)n*9216 + j] = f2bf(ge);
      }
    }
  }
}

// ---------------- MLP down + residual: out = z1 + v3 @ W_down + b_down ----------------------
__global__ __launch_bounds__(256) void k_down(
    const ushort* __restrict__ v3, const ushort* __restrict__ wdnT,
    const float* __restrict__ z1, const float* __restrict__ bdn,
    float* __restrict__ out)
{
  __shared__ char sA[16384], sB[16384];
  const int m0 = blockIdx.x*128, n0 = blockIdx.y*128;
  f32x4 acc[4][4] = {};
  gemm_core<false,64>((const char*)v3, nullptr, (const char*)wdnT, nullptr,
                      9216, 18432, 18432, m0, n0, acc, sA, nullptr, sB, nullptr);
  const int tid = threadIdx.x, wave = tid>>6, lane = tid&63;
  const int l15 = lane&15, l4 = lane>>4;
  const int wr = (wave>>1)*64, wc = (wave&1)*64;
  #pragma unroll
  for (int mi = 0; mi < 4; ++mi) {
    #pragma unroll
    for (int ni = 0; ni < 4; ++ni) {
      const int d = n0 + wc + ni*16 + l15;
      const float bd = bdn[d];
      #pragma unroll
      for (int r = 0; r < 4; ++r) {
        const int n = m0 + wr + mi*16 + l4*4 + r;
        out[(size_t)n*768 + d] = z1[(size_t)n*768 + d] + acc[mi][ni][r] + bd;
      }
    }
  }
}

extern "C" void kernel_launch(void* const* d_in, const int* in_sizes, int n_in,
                              void* d_out, int out_size, void* d_ws, size_t ws_size,
                              hipStream_t stream) {
  const float* x   = (const float*)d_in[0];
  const int*   am  = (const int*)d_in[1];
  const float* WQ  = (const float*)d_in[2];
  const float* WK  = (const float*)d_in[3];
  const float* WV  = (const float*)d_in[4];
  const float* g1  = (const float*)d_in[5];
  const float* b1  = (const float*)d_in[6];
  const float* g2  = (const float*)d_in[7];
  const float* b2  = (const float*)d_in[8];
  const float* WO  = (const float*)d_in[9];
  const float* Wup = (const float*)d_in[10];
  const float* bup = (const float*)d_in[11];
  const float* Wdn = (const float*)d_in[12];
  const float* bdn = (const float*)d_in[13];
  float* out = (float*)d_out;

  char* w = (char*)d_ws;
  // weight conversions (persistent through their consumers)
  ushort* wqh  = (ushort*)(w + 0);
  ushort* wql  = (ushort*)(w + 1179648);
  ushort* wkh  = (ushort*)(w + 2359296);
  ushort* wkl  = (ushort*)(w + 3538944);
  ushort* wvb  = (ushort*)(w + 4718592);
  ushort* wob  = (ushort*)(w + 5898240);
  ushort* wupT = (ushort*)(w + 7077888);    // [9216][768] bf16
  ushort* wdnT = (ushort*)(w + 21233664);   // [768][9216] bf16
  float*  z1   = (float*) (w + 35389440);   // [4096][768] fp32
  ushort* v1h  = (ushort*)(w + 47972352);   // [4096][768] bf16
  char*  pool  = w + 54263808;              // 75.5MB pool (attn-phase bufs, then v3)
  ushort* uh   = (ushort*)(pool + 0);
  ushort* ul   = (ushort*)(pool + 6291456);
  ushort* Qh_  = (ushort*)(pool + 12582912);
  ushort* Ql_  = (ushort*)(pool + 18874368);
  ushort* Kh_  = (ushort*)(pool + 25165824);
  ushort* Kl_  = (ushort*)(pool + 31457280);
  ushort* Vt_  = (ushort*)(pool + 37748736);
  ushort* oc   = (ushort*)(pool + 44040192);
  ushort* v3   = (ushort*)(pool + 0);       // overlaps dead attn-phase buffers
  const size_t NEED = 54263808u + 75497472u;
  if (ws_size < NEED) return;               // fail cleanly rather than corrupt

  k_prep<<<2304, 256, 0, stream>>>(WQ, WK, WV, WO, wqh, wql, wkh, wkl, wvb, wob);
  k_transpose<<<dim3(288, 24), 256, 0, stream>>>(Wup, wupT, 768, 9216);
  k_transpose<<<dim3(24, 288), 256, 0, stream>>>(Wdn, wdnT, 9216, 768);
  k_ln<<<4096, 256, 0, stream>>>(x, g1, b1, uh, ul);
  k_qkv<<<dim3(32, 6, 3), 256, 0, stream>>>(uh, ul, wqh, wql, wkh, wkl, wvb,
                                            Qh_, Ql_, Kh_, Kl_, Vt_);
  k_attn<<<dim3(32, 24), 256, 0, stream>>>(Qh_, Ql_, Kh_, Kl_, Vt_, am, oc);
  k_wo<<<dim3(32, 6), 256, 0, stream>>>(oc, wob, x, z1);
  k_ln<<<4096, 256, 0, stream>>>(z1, g2, b2, v1h, nullptr);
  k_up<<<dim3(32, 72), 256, 0, stream>>>(v1h, wupT, bup, v3);
  k_down<<<dim3(32, 6), 256, 0, stream>>>(v3, wdnT, z1, bdn, out);
}

// Round 2
// 530.938 us; speedup vs baseline: 1.0474x; 1.0474x over previous
//
#include <hip/hip_runtime.h>
#include <stdint.h>

typedef __attribute__((ext_vector_type(8))) short bf16x8;   // 8 bf16 in 4 VGPRs
typedef __attribute__((ext_vector_type(4))) float f32x4;
typedef __attribute__((ext_vector_type(4))) unsigned short us4;
typedef unsigned short ushort;
typedef unsigned int uint;

#define MFMA16(a,b,c) __builtin_amdgcn_mfma_f32_16x16x32_bf16((a),(b),(c),0,0,0)

__device__ __forceinline__ ushort f2bf(float f){
  uint u = __builtin_bit_cast(uint, f);
  return (ushort)((u + 0x7fffu + ((u>>16)&1u)) >> 16);   // RTNE
}
__device__ __forceinline__ float bf2f(ushort h){
  return __builtin_bit_cast(float, ((uint)h)<<16);
}
__device__ __forceinline__ void gll16(const void* g, void* l){
  // async global->LDS, 16B per lane; LDS dest must be wave-uniform base (HW adds lane*16)
  __builtin_amdgcn_global_load_lds((const __attribute__((address_space(1))) void*)g,
                                   (__attribute__((address_space(3))) void*)l, 16, 0, 0);
}

// ---------------- generic 128x128 GEMM core (A row-major [.,K], B^T row-major [N,K], bf16) ---
// SPLIT: C = Ah*Bh + Ah*Bl + Al*Bh  (split-precision bf16 hi/lo)
template<bool SPLIT, int BK>
__device__ __forceinline__ void gemm_core(
    const char* __restrict__ Ah, const char* __restrict__ Al,
    const char* __restrict__ Bh, const char* __restrict__ Bl,
    int K, int lda, int ldb, int m0, int n0,
    f32x4 acc[4][4], char* sAh, char* sAl, char* sBh, char* sBl)
{
  constexpr int ROWB = BK*2;               // bytes per LDS row
  constexpr int CHUNKS = 128*ROWB/1024;    // 1KB wave-chunks per tile
  constexpr int XM = ((ROWB/16)-1) & 7;    // XOR-swizzle mask (16B granules per row)
  const int tid = threadIdx.x;
  const int wave = tid>>6, lane = tid&63;
  const int l15 = lane&15, l4 = lane>>4;
  const int wr = (wave>>1)*64, wc = (wave&1)*64;
  const int nsteps = K / BK;
  for (int kt = 0; kt < nsteps; ++kt) {
    const int kb0 = kt*ROWB;
    for (int c = wave; c < CHUNKS; c += 4) {
      const int p = (c<<10) + (lane<<4);
      const int row = p / ROWB;
      const int gk = (p % ROWB) ^ ((row & XM)<<4);   // pre-swizzled global source
      gll16(Ah + (size_t)(m0+row)*lda + kb0 + gk, sAh + (c<<10));
      gll16(Bh + (size_t)(n0+row)*ldb + kb0 + gk, sBh + (c<<10));
      if constexpr (SPLIT) {
        gll16(Al + (size_t)(m0+row)*lda + kb0 + gk, sAl + (c<<10));
        gll16(Bl + (size_t)(n0+row)*ldb + kb0 + gk, sBl + (c<<10));
      }
    }
    __syncthreads();
    #pragma unroll
    for (int ks = 0; ks < BK/32; ++ks) {
      bf16x8 ah[4], bh_[4], al[4], bl[4];
      #pragma unroll
      for (int i = 0; i < 4; ++i) {
        const int ar = wr + i*16 + l15;
        const int ao = ar*ROWB + ((ks*64 + l4*16) ^ ((ar & XM)<<4));
        ah[i] = *(const bf16x8*)(sAh + ao);
        const int br = wc + i*16 + l15;
        const int bo = br*ROWB + ((ks*64 + l4*16) ^ ((br & XM)<<4));
        bh_[i] = *(const bf16x8*)(sBh + bo);
        if constexpr (SPLIT) {
          al[i] = *(const bf16x8*)(sAl + ao);
          bl[i] = *(const bf16x8*)(sBl + bo);
        }
      }
      #pragma unroll
      for (int mi = 0; mi < 4; ++mi) {
        #pragma unroll
        for (int ni = 0; ni < 4; ++ni) {
          acc[mi][ni] = MFMA16(ah[mi], bh_[ni], acc[mi][ni]);
          if constexpr (SPLIT) {
            acc[mi][ni] = MFMA16(ah[mi], bl[ni], acc[mi][ni]);
            acc[mi][ni] = MFMA16(al[mi], bh_[ni], acc[mi][ni]);
          }
        }
      }
    }
    __syncthreads();
  }
}

// ---------------- weight prep: split WQ/WK into bf16 hi/lo, convert WV/W_O -------------------
__global__ __launch_bounds__(256) void k_prep(
    const float* __restrict__ wq, const float* __restrict__ wk,
    const float* __restrict__ wv, const float* __restrict__ wo,
    ushort* qh, ushort* ql_, ushort* kh, ushort* kl_, ushort* vb, ushort* ob)
{
  int i = blockIdx.x*256 + threadIdx.x;
  if (i >= 589824) return;
  float a = wq[i]; ushort h = f2bf(a); qh[i]=h; ql_[i]=f2bf(a - bf2f(h));
  float b = wk[i]; h = f2bf(b); kh[i]=h; kl_[i]=f2bf(b - bf2f(h));
  vb[i] = f2bf(wv[i]); ob[i] = f2bf(wo[i]);
}

// ---------------- fp32 [R][C] -> bf16 [C][R] transpose --------------------------------------
__global__ __launch_bounds__(256) void k_transpose(
    const float* __restrict__ in, ushort* __restrict__ out, int R, int C)
{
  __shared__ float t[32][33];
  const int bx = blockIdx.x*32, by = blockIdx.y*32;
  const int tx = threadIdx.x & 31, ty = threadIdx.x >> 5;
  #pragma unroll
  for (int i = 0; i < 4; ++i)
    t[ty + i*8][tx] = in[(size_t)(by + ty + i*8)*C + bx + tx];
  __syncthreads();
  #pragma unroll
  for (int i = 0; i < 4; ++i)
    out[(size_t)(bx + ty + i*8)*R + by + tx] = f2bf(t[tx][ty + i*8]);
}

// ---------------- layernorm over 768, fp32 in -> bf16 hi (+optional lo) ---------------------
__global__ __launch_bounds__(256) void k_ln(
    const float* __restrict__ in, const float* __restrict__ g, const float* __restrict__ be,
    ushort* __restrict__ oh, ushort* __restrict__ ol)
{
  const int row = blockIdx.x, t = threadIdx.x;
  const float* r = in + (size_t)row*768;
  float v0 = r[t], v1 = r[t+256], v2 = r[t+512];
  float s = v0+v1+v2;
  float q = v0*v0 + v1*v1 + v2*v2;
  #pragma unroll
  for (int m = 32; m; m >>= 1) { s += __shfl_xor(s, m); q += __shfl_xor(q, m); }
  __shared__ float ss[4], sq[4];
  const int wave = t>>6, lane = t&63;
  if (!lane) { ss[wave] = s; sq[wave] = q; }
  __syncthreads();
  s = ss[0]+ss[1]+ss[2]+ss[3];
  q = sq[0]+sq[1]+sq[2]+sq[3];
  const float mu = s*(1.f/768.f);
  const float var = q*(1.f/768.f) - mu*mu;
  const float inv = rsqrtf(var + 1e-5f);
  const float vv[3] = {v0, v1, v2};
  #pragma unroll
  for (int i = 0; i < 3; ++i) {
    const int idx = t + i*256;
    const float u = (vv[i]-mu)*inv*g[idx] + be[idx];
    const ushort hi = f2bf(u);
    oh[(size_t)row*768 + idx] = hi;
    if (ol) ol[(size_t)row*768 + idx] = f2bf(u - bf2f(hi));
  }
}

// ---------------- QKV projection: z=0 Q(split), z=1 K(split), z=2 V(plain, writes V^T) ------
__global__ __launch_bounds__(256) void k_qkv(
    const ushort* __restrict__ uh, const ushort* __restrict__ ul,
    const ushort* __restrict__ wqh, const ushort* __restrict__ wql,
    const ushort* __restrict__ wkh, const ushort* __restrict__ wkl,
    const ushort* __restrict__ wvb,
    ushort* __restrict__ Qh, ushort* __restrict__ Ql,
    ushort* __restrict__ Kh, ushort* __restrict__ Kl,
    ushort* __restrict__ Vt)
{
  __shared__ char sA[8192], sA2[8192], sB[8192], sB2[8192];
  const int z = blockIdx.z;
  const int m0 = blockIdx.x*128, n0 = blockIdx.y*128;
  f32x4 acc[4][4] = {};
  if (z == 0)
    gemm_core<true,32>((const char*)uh, (const char*)ul, (const char*)wqh, (const char*)wql,
                       768, 1536, 1536, m0, n0, acc, sA, sA2, sB, sB2);
  else if (z == 1)
    gemm_core<true,32>((const char*)uh, (const char*)ul, (const char*)wkh, (const char*)wkl,
                       768, 1536, 1536, m0, n0, acc, sA, sA2, sB, sB2);
  else
    gemm_core<false,32>((const char*)uh, nullptr, (const char*)wvb, nullptr,
                        768, 1536, 1536, m0, n0, acc, sA, sA2, sB, sB2);

  const int tid = threadIdx.x, wave = tid>>6, lane = tid&63;
  const int l15 = lane&15, l4 = lane>>4;
  const int wr = (wave>>1)*64, wc = (wave&1)*64;
  if (z < 2) {
    ushort* __restrict__ Oh = z ? Kh : Qh;
    ushort* __restrict__ Ol = z ? Kl : Ql;
    #pragma unroll
    for (int mi = 0; mi < 4; ++mi) {
      #pragma unroll
      for (int ni = 0; ni < 4; ++ni) {
        const int he = n0 + wc + ni*16 + l15;
        const int h = he>>6, e = he&63;
        #pragma unroll
        for (int r = 0; r < 4; ++r) {
          const int n = m0 + wr + mi*16 + l4*4 + r;
          const int b = n>>11, l = n&2047;
          const size_t dst = ((size_t)((b*12+h)*2048 + l))*64 + e;
          const float c = acc[mi][ni][r];
          const ushort hi = f2bf(c);
          Oh[dst] = hi;
          Ol[dst] = f2bf(c - bf2f(hi));
        }
      }
    }
  } else {
    #pragma unroll
    for (int mi = 0; mi < 4; ++mi) {
      #pragma unroll
      for (int ni = 0; ni < 4; ++ni) {
        const int he = n0 + wc + ni*16 + l15;
        const int h = he>>6, e = he&63;
        const int n = m0 + wr + mi*16 + l4*4;
        const int b = n>>11, l = n&2047;
        us4 v;
        #pragma unroll
        for (int r = 0; r < 4; ++r) v[r] = f2bf(acc[mi][ni][r]);
        *(us4*)(Vt + ((size_t)((b*12+h)*64 + e))*2048 + l) = v;
      }
    }
  }
}

// ---------------- fused causal attention, tanh-clipped, no-rescale online softmax -----------
// grid (32 qtiles, 24 bh); block 256; BQ=BKV=64; wave w owns q rows w*16..w*16+15
__global__ __launch_bounds__(256) void k_attn(
    const ushort* __restrict__ Qh, const ushort* __restrict__ Ql,
    const ushort* __restrict__ Kh, const ushort* __restrict__ Kl,
    const ushort* __restrict__ Vt, const int* __restrict__ am,
    ushort* __restrict__ Oc)
{
  __shared__ char sKh[8192], sKl[8192], sV[8192];
  __shared__ char sP[4][2048];
  const int qt = gridDim.x - 1 - blockIdx.x;    // big tiles first
  const int bh = blockIdx.y;
  const int b = bh / 12, h = bh - b*12;
  const int tid = threadIdx.x, wave = tid>>6, lane = tid&63;
  const int l15 = lane&15, l4 = lane>>4;

  const size_t qoff = ((size_t)bh*2048 + qt*64 + wave*16 + l15)*64 + l4*8;
  const bf16x8 q_h0 = *(const bf16x8*)(Qh + qoff);
  const bf16x8 q_h1 = *(const bf16x8*)(Qh + qoff + 32);
  const bf16x8 q_l0 = *(const bf16x8*)(Ql + qoff);
  const bf16x8 q_l1 = *(const bf16x8*)(Ql + qoff + 32);

  f32x4 oacc[4] = {};
  float dsum[4] = {0.f, 0.f, 0.f, 0.f};
  const char* Kh_t = (const char*)(Kh + (size_t)bh*2048*64);
  const char* Kl_t = (const char*)(Kl + (size_t)bh*2048*64);
  const char* Vt_b = (const char*)(Vt + (size_t)bh*64*2048);

  for (int kt = 0; kt <= qt; ++kt) {
    // stage K_hi/K_lo [64 key][64 e] and V^T [64 e][64 key] tiles, XOR-swizzled via source
    for (int c = wave; c < 24; c += 4) {
      const int p = ((c&7)<<10) + (lane<<4);
      const int row = p >> 7;
      const int gkb = (p & 127) ^ ((row&7)<<4);
      const char* gsrc; char* lbase;
      if (c < 8)       { gsrc = Kh_t + (size_t)(kt*64+row)*128 + gkb; lbase = sKh + ((c&7)<<10); }
      else if (c < 16) { gsrc = Kl_t + (size_t)(kt*64+row)*128 + gkb; lbase = sKl + ((c&7)<<10); }
      else             { gsrc = Vt_b + (size_t)row*4096 + kt*128 + gkb; lbase = sV + ((c&7)<<10); }
      gll16(gsrc, lbase);
    }
    __syncthreads();

    // S = Q K^T (3-term split product)
    f32x4 s[4] = {};
    #pragma unroll
    for (int ks = 0; ks < 2; ++ks) {
      bf16x8 kbh[4], kbl[4];
      #pragma unroll
      for (int nt = 0; nt < 4; ++nt) {
        const int key = nt*16 + l15;
        const int byte = key*128 + ((ks*64 + l4*16) ^ ((key&7)<<4));
        kbh[nt] = *(const bf16x8*)(sKh + byte);
        kbl[nt] = *(const bf16x8*)(sKl + byte);
      }
      const bf16x8 qh_ = ks ? q_h1 : q_h0;
      const bf16x8 ql_ = ks ? q_l1 : q_l0;
      #pragma unroll
      for (int nt = 0; nt < 4; ++nt) {
        s[nt] = MFMA16(qh_, kbh[nt], s[nt]);
        s[nt] = MFMA16(qh_, kbl[nt], s[nt]);
        s[nt] = MFMA16(ql_, kbh[nt], s[nt]);
      }
    }

    // tanh clip + causal + pad mask + exp(S-30); stash P (bf16) in per-wave LDS
    // 30*tanh(s) - 30 == -60/(1+e^{2s})  -> p = exp(-60/(1+exp(2s)))
    const bool diag = (kt == qt);
    #pragma unroll
    for (int nt = 0; nt < 4; ++nt) {
      const int key_g = kt*64 + nt*16 + l15;
      const float mv = (float)am[b*2048 + key_g];
      #pragma unroll
      for (int r = 0; r < 4; ++r) {
        const float sv = s[nt][r]*0.125f;
        float p = __expf(-60.f/(1.f + __expf(2.f*sv))) * mv;
        if (diag && key_g > qt*64 + wave*16 + l4*4 + r) p = 0.f;
        dsum[r] += p;
        const int qi = l4*4 + r;
        const int byte = qi*128 + ((nt*32 + l15*2) ^ ((qi&7)<<4));
        *(ushort*)(sP[wave] + byte) = f2bf(p);
      }
    }

    // O += P V
    #pragma unroll
    for (int ks = 0; ks < 2; ++ks) {
      const int abyte = l15*128 + ((ks*64 + l4*16) ^ ((l15&7)<<4));
      const bf16x8 pa = *(const bf16x8*)(sP[wave] + abyte);
      #pragma unroll
      for (int et = 0; et < 4; ++et) {
        const int e_l = et*16 + l15;
        const int vbyte = e_l*128 + ((ks*64 + l4*16) ^ ((e_l&7)<<4));
        const bf16x8 vb = *(const bf16x8*)(sV + vbyte);
        oacc[et] = MFMA16(pa, vb, oacc[et]);
      }
    }
    __syncthreads();
  }

  #pragma unroll
  for (int r = 0; r < 4; ++r) {
    float d = dsum[r];
    d += __shfl_xor(d, 1); d += __shfl_xor(d, 2);
    d += __shfl_xor(d, 4); d += __shfl_xor(d, 8);
    dsum[r] = 1.f/d;
  }
  #pragma unroll
  for (int et = 0; et < 4; ++et) {
    #pragma unroll
    for (int r = 0; r < 4; ++r) {
      const int q_g = qt*64 + wave*16 + l4*4 + r;
      const size_t n = (size_t)b*2048 + q_g;
      const int he = h*64 + et*16 + l15;
      Oc[n*768 + he] = f2bf(oacc[et][r]*dsum[r]);
    }
  }
}

// ---------------- W_O GEMM, split-K=2, atomic accumulate into z1 (pre-init = x) -------------
__global__ __launch_bounds__(256) void k_wo(
    const ushort* __restrict__ oc, const ushort* __restrict__ wob,
    float* __restrict__ z1)
{
  __shared__ char sA[16384], sB[16384];
  const int m0 = blockIdx.x*128, n0 = blockIdx.y*128;
  const int kz = blockIdx.z;               // K chunk: 384 elements = 768 bytes
  f32x4 acc[4][4] = {};
  gemm_core<false,64>((const char*)oc + kz*768, nullptr, (const char*)wob + kz*768, nullptr,
                      384, 1536, 1536, m0, n0, acc, sA, nullptr, sB, nullptr);
  const int tid = threadIdx.x, wave = tid>>6, lane = tid&63;
  const int l15 = lane&15, l4 = lane>>4;
  const int wr = (wave>>1)*64, wc = (wave&1)*64;
  #pragma unroll
  for (int mi = 0; mi < 4; ++mi) {
    #pragma unroll
    for (int ni = 0; ni < 4; ++ni) {
      const int d = n0 + wc + ni*16 + l15;
      #pragma unroll
      for (int r = 0; r < 4; ++r) {
        const int n = m0 + wr + mi*16 + l4*4 + r;
        unsafeAtomicAdd(&z1[(size_t)n*768 + d], acc[mi][ni][r]);
      }
    }
  }
}

// ---------------- MLP up: v3 = gelu(v1 @ W_up + b_up) ---------------------------------------
__global__ __launch_bounds__(256) void k_up(
    const ushort* __restrict__ v1, const ushort* __restrict__ wupT,
    const float* __restrict__ bup, ushort* __restrict__ v3)
{
  __shared__ char sA[16384], sB[16384];
  const int m0 = blockIdx.x*128, n0 = blockIdx.y*128;
  f32x4 acc[4][4] = {};
  gemm_core<false,64>((const char*)v1, nullptr, (const char*)wupT, nullptr,
                      768, 1536, 1536, m0, n0, acc, sA, nullptr, sB, nullptr);
  const int tid = threadIdx.x, wave = tid>>6, lane = tid&63;
  const int l15 = lane&15, l4 = lane>>4;
  const int wr = (wave>>1)*64, wc = (wave&1)*64;
  #pragma unroll
  for (int mi = 0; mi < 4; ++mi) {
    #pragma unroll
    for (int ni = 0; ni < 4; ++ni) {
      const int j = n0 + wc + ni*16 + l15;
      const float bj = bup[j];
      #pragma unroll
      for (int r = 0; r < 4; ++r) {
        const int n = m0 + wr + mi*16 + l4*4 + r;
        const float c = acc[mi][ni][r] + bj;
        const float ge = 0.5f*c*(1.f + erff(c*0.70710678118654752f));
        v3[(size_t)n*9216 + j] = f2bf(ge);
      }
    }
  }
}

// ---------------- out init: out = z1 + b_down -----------------------------------------------
__global__ __launch_bounds__(256) void k_oinit(
    const float* __restrict__ z1, const float* __restrict__ bdn, float* __restrict__ out)
{
  const int i = blockIdx.x*256 + threadIdx.x;      // float4 index; 768%4==0 so no row wrap
  const f32x4 z = *(const f32x4*)(z1 + (size_t)i*4);
  const int d = (i*4) % 768;
  f32x4 o;
  #pragma unroll
  for (int j = 0; j < 4; ++j) o[j] = z[j] + bdn[d+j];
  *(f32x4*)(out + (size_t)i*4) = o;
}

// ---------------- MLP down, split-K=4, atomic accumulate into out (pre-init z1+b) -----------
__global__ __launch_bounds__(256) void k_down(
    const ushort* __restrict__ v3, const ushort* __restrict__ wdnT,
    float* __restrict__ out)
{
  __shared__ char sA[16384], sB[16384];
  const int m0 = blockIdx.x*128, n0 = blockIdx.y*128;
  const int kz = blockIdx.z;               // K chunk: 2304 elements = 4608 bytes
  f32x4 acc[4][4] = {};
  gemm_core<false,64>((const char*)v3 + kz*4608, nullptr, (const char*)wdnT + kz*4608, nullptr,
                      2304, 18432, 18432, m0, n0, acc, sA, nullptr, sB, nullptr);
  const int tid = threadIdx.x, wave = tid>>6, lane = tid&63;
  const int l15 = lane&15, l4 = lane>>4;
  const int wr = (wave>>1)*64, wc = (wave&1)*64;
  #pragma unroll
  for (int mi = 0; mi < 4; ++mi) {
    #pragma unroll
    for (int ni = 0; ni < 4; ++ni) {
      const int d = n0 + wc + ni*16 + l15;
      #pragma unroll
      for (int r = 0; r < 4; ++r) {
        const int n = m0 + wr + mi*16 + l4*4 + r;
        unsafeAtomicAdd(&out[(size_t)n*768 + d], acc[mi][ni][r]);
      }
    }
  }
}

extern "C" void kernel_launch(void* const* d_in, const int* in_sizes, int n_in,
                              void* d_out, int out_size, void* d_ws, size_t ws_size,
                              hipStream_t stream) {
  const float* x   = (const float*)d_in[0];
  const int*   am  = (const int*)d_in[1];
  const float* WQ  = (const float*)d_in[2];
  const float* WK  = (const float*)d_in[3];
  const float* WV  = (const float*)d_in[4];
  const float* g1  = (const float*)d_in[5];
  const float* b1  = (const float*)d_in[6];
  const float* g2  = (const float*)d_in[7];
  const float* b2  = (const float*)d_in[8];
  const float* WO  = (const float*)d_in[9];
  const float* Wup = (const float*)d_in[10];
  const float* bup = (const float*)d_in[11];
  const float* Wdn = (const float*)d_in[12];
  const float* bdn = (const float*)d_in[13];
  float* out = (float*)d_out;

  char* w = (char*)d_ws;
  // weight conversions (persistent through their consumers)
  ushort* wqh  = (ushort*)(w + 0);
  ushort* wql  = (ushort*)(w + 1179648);
  ushort* wkh  = (ushort*)(w + 2359296);
  ushort* wkl  = (ushort*)(w + 3538944);
  ushort* wvb  = (ushort*)(w + 4718592);
  ushort* wob  = (ushort*)(w + 5898240);
  ushort* wupT = (ushort*)(w + 7077888);    // [9216][768] bf16
  ushort* wdnT = (ushort*)(w + 21233664);   // [768][9216] bf16
  float*  z1   = (float*) (w + 35389440);   // [4096][768] fp32
  ushort* v1h  = (ushort*)(w + 47972352);   // [4096][768] bf16
  char*  pool  = w + 54263808;              // 75.5MB pool (attn-phase bufs, then v3)
  ushort* uh   = (ushort*)(pool + 0);
  ushort* ul   = (ushort*)(pool + 6291456);
  ushort* Qh_  = (ushort*)(pool + 12582912);
  ushort* Ql_  = (ushort*)(pool + 18874368);
  ushort* Kh_  = (ushort*)(pool + 25165824);
  ushort* Kl_  = (ushort*)(pool + 31457280);
  ushort* Vt_  = (ushort*)(pool + 37748736);
  ushort* oc   = (ushort*)(pool + 44040192);
  ushort* v3   = (ushort*)(pool + 0);       // overlaps dead attn-phase buffers
  const size_t NEED = 54263808u + 75497472u;
  if (ws_size < NEED) return;               // fail cleanly rather than corrupt

  k_prep<<<2304, 256, 0, stream>>>(WQ, WK, WV, WO, wqh, wql, wkh, wkl, wvb, wob);
  k_transpose<<<dim3(288, 24), 256, 0, stream>>>(Wup, wupT, 768, 9216);
  k_transpose<<<dim3(24, 288), 256, 0, stream>>>(Wdn, wdnT, 9216, 768);
  k_ln<<<4096, 256, 0, stream>>>(x, g1, b1, uh, ul);
  k_qkv<<<dim3(32, 6, 3), 256, 0, stream>>>(uh, ul, wqh, wql, wkh, wkl, wvb,
                                            Qh_, Ql_, Kh_, Kl_, Vt_);
  k_attn<<<dim3(32, 24), 256, 0, stream>>>(Qh_, Ql_, Kh_, Kl_, Vt_, am, oc);
  // z1 = x, then W_O GEMM atomically accumulates (split-K=2, 384 blocks)
  hipMemcpyAsync(z1, x, 12582912, hipMemcpyDeviceToDevice, stream);
  k_wo<<<dim3(32, 6, 2), 256, 0, stream>>>(oc, wob, z1);
  k_ln<<<4096, 256, 0, stream>>>(z1, g2, b2, v1h, nullptr);
  k_up<<<dim3(32, 72), 256, 0, stream>>>(v1h, wupT, bup, v3);
  // out = z1 + b_down, then MLP-down atomically accumulates (split-K=4, 768 blocks)
  k_oinit<<<3072, 256, 0, stream>>>(z1, bdn, out);
  k_down<<<dim3(32, 6, 4), 256, 0, stream>>>(v3, wdnT, out);
}

// Round 3
// 492.656 us; speedup vs baseline: 1.1288x; 1.0777x over previous
//
#include <hip/hip_runtime.h>
#include <stdint.h>

typedef __attribute__((ext_vector_type(8))) short bf16x8;   // 8 bf16 in 4 VGPRs
typedef __attribute__((ext_vector_type(4))) float f32x4;
typedef __attribute__((ext_vector_type(4))) unsigned short us4;
typedef unsigned short ushort;
typedef unsigned int uint;

#define MFMA16(a,b,c) __builtin_amdgcn_mfma_f32_16x16x32_bf16((a),(b),(c),0,0,0)

__device__ __forceinline__ ushort f2bf(float f){
  uint u = __builtin_bit_cast(uint, f);
  return (ushort)((u + 0x7fffu + ((u>>16)&1u)) >> 16);   // RTNE
}
__device__ __forceinline__ float bf2f(ushort h){
  return __builtin_bit_cast(float, ((uint)h)<<16);
}
__device__ __forceinline__ void gll16(const void* g, void* l){
  // async global->LDS, 16B per lane; LDS dest must be wave-uniform base (HW adds lane*16)
  __builtin_amdgcn_global_load_lds((const __attribute__((address_space(1))) void*)g,
                                   (__attribute__((address_space(3))) void*)l, 16, 0, 0);
}

// ---------------- generic 128x128 GEMM core (A row-major [.,K], B^T row-major [N,K], bf16) ---
// SPLIT: C = Ah*Bh + Ah*Bl + Al*Bh  (split-precision bf16 hi/lo)
template<bool SPLIT, int BK>
__device__ __forceinline__ void gemm_core(
    const char* __restrict__ Ah, const char* __restrict__ Al,
    const char* __restrict__ Bh, const char* __restrict__ Bl,
    int K, int lda, int ldb, int m0, int n0,
    f32x4 acc[4][4], char* sAh, char* sAl, char* sBh, char* sBl)
{
  constexpr int ROWB = BK*2;               // bytes per LDS row
  constexpr int CHUNKS = 128*ROWB/1024;    // 1KB wave-chunks per tile
  constexpr int XM = ((ROWB/16)-1) & 7;    // XOR-swizzle mask (16B granules per row)
  const int tid = threadIdx.x;
  const int wave = tid>>6, lane = tid&63;
  const int l15 = lane&15, l4 = lane>>4;
  const int wr = (wave>>1)*64, wc = (wave&1)*64;
  const int nsteps = K / BK;
  for (int kt = 0; kt < nsteps; ++kt) {
    const int kb0 = kt*ROWB;
    for (int c = wave; c < CHUNKS; c += 4) {
      const int p = (c<<10) + (lane<<4);
      const int row = p / ROWB;
      const int gk = (p % ROWB) ^ ((row & XM)<<4);   // pre-swizzled global source
      gll16(Ah + (size_t)(m0+row)*lda + kb0 + gk, sAh + (c<<10));
      gll16(Bh + (size_t)(n0+row)*ldb + kb0 + gk, sBh + (c<<10));
      if constexpr (SPLIT) {
        gll16(Al + (size_t)(m0+row)*lda + kb0 + gk, sAl + (c<<10));
        gll16(Bl + (size_t)(n0+row)*ldb + kb0 + gk, sBl + (c<<10));
      }
    }
    __syncthreads();
    #pragma unroll
    for (int ks = 0; ks < BK/32; ++ks) {
      bf16x8 ah[4], bh_[4], al[4], bl[4];
      #pragma unroll
      for (int i = 0; i < 4; ++i) {
        const int ar = wr + i*16 + l15;
        const int ao = ar*ROWB + ((ks*64 + l4*16) ^ ((ar & XM)<<4));
        ah[i] = *(const bf16x8*)(sAh + ao);
        const int br = wc + i*16 + l15;
        const int bo = br*ROWB + ((ks*64 + l4*16) ^ ((br & XM)<<4));
        bh_[i] = *(const bf16x8*)(sBh + bo);
        if constexpr (SPLIT) {
          al[i] = *(const bf16x8*)(sAl + ao);
          bl[i] = *(const bf16x8*)(sBl + bo);
        }
      }
      #pragma unroll
      for (int mi = 0; mi < 4; ++mi) {
        #pragma unroll
        for (int ni = 0; ni < 4; ++ni) {
          acc[mi][ni] = MFMA16(ah[mi], bh_[ni], acc[mi][ni]);
          if constexpr (SPLIT) {
            acc[mi][ni] = MFMA16(ah[mi], bl[ni], acc[mi][ni]);
            acc[mi][ni] = MFMA16(al[mi], bh_[ni], acc[mi][ni]);
          }
        }
      }
    }
    __syncthreads();
  }
}

// ---------------- weight prep: split WQ/WK into bf16 hi/lo, convert WV/W_O -------------------
__global__ __launch_bounds__(256) void k_prep(
    const float* __restrict__ wq, const float* __restrict__ wk,
    const float* __restrict__ wv, const float* __restrict__ wo,
    ushort* qh, ushort* ql_, ushort* kh, ushort* kl_, ushort* vb, ushort* ob)
{
  int i = blockIdx.x*256 + threadIdx.x;
  if (i >= 589824) return;
  float a = wq[i]; ushort h = f2bf(a); qh[i]=h; ql_[i]=f2bf(a - bf2f(h));
  float b = wk[i]; h = f2bf(b); kh[i]=h; kl_[i]=f2bf(b - bf2f(h));
  vb[i] = f2bf(wv[i]); ob[i] = f2bf(wo[i]);
}

// ---------------- fp32 [R][C] -> bf16 [C][R] transpose --------------------------------------
__global__ __launch_bounds__(256) void k_transpose(
    const float* __restrict__ in, ushort* __restrict__ out, int R, int C)
{
  __shared__ float t[32][33];
  const int bx = blockIdx.x*32, by = blockIdx.y*32;
  const int tx = threadIdx.x & 31, ty = threadIdx.x >> 5;
  #pragma unroll
  for (int i = 0; i < 4; ++i)
    t[ty + i*8][tx] = in[(size_t)(by + ty + i*8)*C + bx + tx];
  __syncthreads();
  #pragma unroll
  for (int i = 0; i < 4; ++i)
    out[(size_t)(bx + ty + i*8)*R + by + tx] = f2bf(t[tx][ty + i*8]);
}

// ---------------- layernorm over 768, fp32 in -> bf16 hi (+optional lo) ---------------------
__global__ __launch_bounds__(256) void k_ln(
    const float* __restrict__ in, const float* __restrict__ g, const float* __restrict__ be,
    ushort* __restrict__ oh, ushort* __restrict__ ol)
{
  const int row = blockIdx.x, t = threadIdx.x;
  const float* r = in + (size_t)row*768;
  float v0 = r[t], v1 = r[t+256], v2 = r[t+512];
  float s = v0+v1+v2;
  float q = v0*v0 + v1*v1 + v2*v2;
  #pragma unroll
  for (int m = 32; m; m >>= 1) { s += __shfl_xor(s, m); q += __shfl_xor(q, m); }
  __shared__ float ss[4], sq[4];
  const int wave = t>>6, lane = t&63;
  if (!lane) { ss[wave] = s; sq[wave] = q; }
  __syncthreads();
  s = ss[0]+ss[1]+ss[2]+ss[3];
  q = sq[0]+sq[1]+sq[2]+sq[3];
  const float mu = s*(1.f/768.f);
  const float var = q*(1.f/768.f) - mu*mu;
  const float inv = rsqrtf(var + 1e-5f);
  const float vv[3] = {v0, v1, v2};
  #pragma unroll
  for (int i = 0; i < 3; ++i) {
    const int idx = t + i*256;
    const float u = (vv[i]-mu)*inv*g[idx] + be[idx];
    const ushort hi = f2bf(u);
    oh[(size_t)row*768 + idx] = hi;
    if (ol) ol[(size_t)row*768 + idx] = f2bf(u - bf2f(hi));
  }
}

// ---------------- QKV projection: z=0 Q(split), z=1 K(split), z=2 V(plain, writes V^T) ------
__global__ __launch_bounds__(256) void k_qkv(
    const ushort* __restrict__ uh, const ushort* __restrict__ ul,
    const ushort* __restrict__ wqh, const ushort* __restrict__ wql,
    const ushort* __restrict__ wkh, const ushort* __restrict__ wkl,
    const ushort* __restrict__ wvb,
    ushort* __restrict__ Qh, ushort* __restrict__ Ql,
    ushort* __restrict__ Kh, ushort* __restrict__ Kl,
    ushort* __restrict__ Vt)
{
  __shared__ char sA[8192], sA2[8192], sB[8192], sB2[8192];
  const int z = blockIdx.z;
  const int m0 = blockIdx.x*128, n0 = blockIdx.y*128;
  f32x4 acc[4][4] = {};
  if (z == 0)
    gemm_core<true,32>((const char*)uh, (const char*)ul, (const char*)wqh, (const char*)wql,
                       768, 1536, 1536, m0, n0, acc, sA, sA2, sB, sB2);
  else if (z == 1)
    gemm_core<true,32>((const char*)uh, (const char*)ul, (const char*)wkh, (const char*)wkl,
                       768, 1536, 1536, m0, n0, acc, sA, sA2, sB, sB2);
  else
    gemm_core<false,32>((const char*)uh, nullptr, (const char*)wvb, nullptr,
                        768, 1536, 1536, m0, n0, acc, sA, sA2, sB, sB2);

  const int tid = threadIdx.x, wave = tid>>6, lane = tid&63;
  const int l15 = lane&15, l4 = lane>>4;
  const int wr = (wave>>1)*64, wc = (wave&1)*64;
  if (z < 2) {
    ushort* __restrict__ Oh = z ? Kh : Qh;
    ushort* __restrict__ Ol = z ? Kl : Ql;
    #pragma unroll
    for (int mi = 0; mi < 4; ++mi) {
      #pragma unroll
      for (int ni = 0; ni < 4; ++ni) {
        const int he = n0 + wc + ni*16 + l15;
        const int h = he>>6, e = he&63;
        #pragma unroll
        for (int r = 0; r < 4; ++r) {
          const int n = m0 + wr + mi*16 + l4*4 + r;
          const int b = n>>11, l = n&2047;
          const size_t dst = ((size_t)((b*12+h)*2048 + l))*64 + e;
          const float c = acc[mi][ni][r];
          const ushort hi = f2bf(c);
          Oh[dst] = hi;
          Ol[dst] = f2bf(c - bf2f(hi));
        }
      }
    }
  } else {
    #pragma unroll
    for (int mi = 0; mi < 4; ++mi) {
      #pragma unroll
      for (int ni = 0; ni < 4; ++ni) {
        const int he = n0 + wc + ni*16 + l15;
        const int h = he>>6, e = he&63;
        const int n = m0 + wr + mi*16 + l4*4;
        const int b = n>>11, l = n&2047;
        us4 v;
        #pragma unroll
        for (int r = 0; r < 4; ++r) v[r] = f2bf(acc[mi][ni][r]);
        *(us4*)(Vt + ((size_t)((b*12+h)*64 + e))*2048 + l) = v;
      }
    }
  }
}

// ---------------- fused causal attention, split-KV, atomic fp32 partial accumulate ----------
// p = exp(30*tanh(S/8) - 30) is max-free -> partial (num, den) over disjoint KV ranges ADD.
// grid (80, 24): 80 = sum over qt of ceil((qt+1)/8) chunks; block 256 = 4 waves x 16 q rows.
__global__ __launch_bounds__(256) void k_attn(
    const ushort* __restrict__ Qh, const ushort* __restrict__ Ql,
    const ushort* __restrict__ Kh, const ushort* __restrict__ Kl,
    const ushort* __restrict__ Vt, const int* __restrict__ am,
    float* __restrict__ Onum, float* __restrict__ Oden)
{
  __shared__ char sKh[8192], sKl[8192], sV[8192];
  __shared__ char sP[4][2048];
  const int f = 79 - blockIdx.x;                // big chunks dispatch first
  int qt, c;
  if (f < 8)       { qt = f;               c = 0; }
  else if (f < 24) { int t = f-8;  qt = 8 +(t>>1); c = t&1; }
  else if (f < 48) { int t = f-24; qt = 16+ t/3;   c = t - (qt-16)*3; }
  else             { int t = f-48; qt = 24+(t>>2); c = t&3; }
  const int kt0 = c*8;
  const int kt1 = (kt0+8 < qt+1) ? kt0+8 : qt+1;

  const int bh = blockIdx.y;
  const int b = bh / 12;
  const int tid = threadIdx.x, wave = tid>>6, lane = tid&63;
  const int l15 = lane&15, l4 = lane>>4;

  const size_t qoff = ((size_t)bh*2048 + qt*64 + wave*16 + l15)*64 + l4*8;
  const bf16x8 q_h0 = *(const bf16x8*)(Qh + qoff);
  const bf16x8 q_h1 = *(const bf16x8*)(Qh + qoff + 32);
  const bf16x8 q_l0 = *(const bf16x8*)(Ql + qoff);
  const bf16x8 q_l1 = *(const bf16x8*)(Ql + qoff + 32);

  f32x4 oacc[4] = {};
  float dsum[4] = {0.f, 0.f, 0.f, 0.f};
  const char* Kh_t = (const char*)(Kh + (size_t)bh*2048*64);
  const char* Kl_t = (const char*)(Kl + (size_t)bh*2048*64);
  const char* Vt_b = (const char*)(Vt + (size_t)bh*64*2048);

  for (int kt = kt0; kt < kt1; ++kt) {
    // stage K_hi/K_lo [64 key][64 e] and V^T [64 e][64 key] tiles, XOR-swizzled via source
    for (int cc = wave; cc < 24; cc += 4) {
      const int p = ((cc&7)<<10) + (lane<<4);
      const int row = p >> 7;
      const int gkb = (p & 127) ^ ((row&7)<<4);
      const char* gsrc; char* lbase;
      if (cc < 8)       { gsrc = Kh_t + (size_t)(kt*64+row)*128 + gkb; lbase = sKh + ((cc&7)<<10); }
      else if (cc < 16) { gsrc = Kl_t + (size_t)(kt*64+row)*128 + gkb; lbase = sKl + ((cc&7)<<10); }
      else              { gsrc = Vt_b + (size_t)row*4096 + kt*128 + gkb; lbase = sV + ((cc&7)<<10); }
      gll16(gsrc, lbase);
    }
    __syncthreads();

    // S = Q K^T (3-term split product)
    f32x4 s[4] = {};
    #pragma unroll
    for (int ks = 0; ks < 2; ++ks) {
      bf16x8 kbh[4], kbl[4];
      #pragma unroll
      for (int nt = 0; nt < 4; ++nt) {
        const int key = nt*16 + l15;
        const int byte = key*128 + ((ks*64 + l4*16) ^ ((key&7)<<4));
        kbh[nt] = *(const bf16x8*)(sKh + byte);
        kbl[nt] = *(const bf16x8*)(sKl + byte);
      }
      const bf16x8 qh_ = ks ? q_h1 : q_h0;
      const bf16x8 ql_ = ks ? q_l1 : q_l0;
      #pragma unroll
      for (int nt = 0; nt < 4; ++nt) {
        s[nt] = MFMA16(qh_, kbh[nt], s[nt]);
        s[nt] = MFMA16(qh_, kbl[nt], s[nt]);
        s[nt] = MFMA16(ql_, kbh[nt], s[nt]);
      }
    }

    // p = exp(-60/(1+e^{2*S/8})); fast rcp is inf-safe: rcp(inf)=0 -> p=1 saturated
    const bool diag = (kt == qt);
    #pragma unroll
    for (int nt = 0; nt < 4; ++nt) {
      const int key_g = kt*64 + nt*16 + l15;
      const float mv = (float)am[b*2048 + key_g];
      #pragma unroll
      for (int r = 0; r < 4; ++r) {
        const float es = __expf(0.25f*s[nt][r]);           // e^{2s}, s = raw/8
        float p = __expf(-60.f*__builtin_amdgcn_rcpf(1.f + es)) * mv;
        if (diag && key_g > qt*64 + wave*16 + l4*4 + r) p = 0.f;
        dsum[r] += p;
        const int qi = l4*4 + r;
        const int byte = qi*128 + ((nt*32 + l15*2) ^ ((qi&7)<<4));
        *(ushort*)(sP[wave] + byte) = f2bf(p);
      }
    }

    // O += P V
    #pragma unroll
    for (int ks = 0; ks < 2; ++ks) {
      const int abyte = l15*128 + ((ks*64 + l4*16) ^ ((l15&7)<<4));
      const bf16x8 pa = *(const bf16x8*)(sP[wave] + abyte);
      #pragma unroll
      for (int et = 0; et < 4; ++et) {
        const int e_l = et*16 + l15;
        const int vbyte = e_l*128 + ((ks*64 + l4*16) ^ ((e_l&7)<<4));
        const bf16x8 vb = *(const bf16x8*)(sV + vbyte);
        oacc[et] = MFMA16(pa, vb, oacc[et]);
      }
    }
    __syncthreads();
  }

  // reduce row-denominators across the 16-lane l15 groups, then atomically combine partials
  #pragma unroll
  for (int r = 0; r < 4; ++r) {
    float d = dsum[r];
    d += __shfl_xor(d, 1); d += __shfl_xor(d, 2);
    d += __shfl_xor(d, 4); d += __shfl_xor(d, 8);
    dsum[r] = d;
  }
  const int qrow = qt*64 + wave*16 + l4*4;
  if (l15 == 0) {
    #pragma unroll
    for (int r = 0; r < 4; ++r)
      unsafeAtomicAdd(&Oden[bh*2048 + qrow + r], dsum[r]);
  }
  #pragma unroll
  for (int et = 0; et < 4; ++et) {
    #pragma unroll
    for (int r = 0; r < 4; ++r)
      unsafeAtomicAdd(&Onum[((size_t)bh*2048 + qrow + r)*64 + et*16 + l15], oacc[et][r]);
  }
}

// ---------------- normalize attention partials -> bf16 O_cat [B*L][768] ---------------------
__global__ __launch_bounds__(256) void k_norm(
    const float* __restrict__ Onum, const float* __restrict__ Oden,
    ushort* __restrict__ Oc)
{
  const int i = blockIdx.x*256 + threadIdx.x;    // f32x4 units over [24][2048][64]
  const int row = i >> 4;                        // bh*2048 + l
  const int e0 = (i & 15)*4;
  const int bh = row >> 11, l = row & 2047;
  const int b = bh / 12, h = bh - b*12;
  const float inv = 1.f / Oden[row];
  const f32x4 v = *(const f32x4*)(Onum + (size_t)i*4);
  us4 o;
  #pragma unroll
  for (int j = 0; j < 4; ++j) o[j] = f2bf(v[j]*inv);
  *(us4*)(Oc + ((size_t)(b*2048 + l))*768 + h*64 + e0) = o;
}

// ---------------- W_O GEMM, split-K=2, atomic accumulate into z1 (pre-init = x) -------------
__global__ __launch_bounds__(256) void k_wo(
    const ushort* __restrict__ oc, const ushort* __restrict__ wob,
    float* __restrict__ z1)
{
  __shared__ char sA[16384], sB[16384];
  const int m0 = blockIdx.x*128, n0 = blockIdx.y*128;
  const int kz = blockIdx.z;               // K chunk: 384 elements = 768 bytes
  f32x4 acc[4][4] = {};
  gemm_core<false,64>((const char*)oc + kz*768, nullptr, (const char*)wob + kz*768, nullptr,
                      384, 1536, 1536, m0, n0, acc, sA, nullptr, sB, nullptr);
  const int tid = threadIdx.x, wave = tid>>6, lane = tid&63;
  const int l15 = lane&15, l4 = lane>>4;
  const int wr = (wave>>1)*64, wc = (wave&1)*64;
  #pragma unroll
  for (int mi = 0; mi < 4; ++mi) {
    #pragma unroll
    for (int ni = 0; ni < 4; ++ni) {
      const int d = n0 + wc + ni*16 + l15;
      #pragma unroll
      for (int r = 0; r < 4; ++r) {
        const int n = m0 + wr + mi*16 + l4*4 + r;
        unsafeAtomicAdd(&z1[(size_t)n*768 + d], acc[mi][ni][r]);
      }
    }
  }
}

// ---------------- MLP up: v3 = gelu(v1 @ W_up + b_up) ---------------------------------------
__global__ __launch_bounds__(256) void k_up(
    const ushort* __restrict__ v1, const ushort* __restrict__ wupT,
    const float* __restrict__ bup, ushort* __restrict__ v3)
{
  __shared__ char sA[16384], sB[16384];
  const int m0 = blockIdx.x*128, n0 = blockIdx.y*128;
  f32x4 acc[4][4] = {};
  gemm_core<false,64>((const char*)v1, nullptr, (const char*)wupT, nullptr,
                      768, 1536, 1536, m0, n0, acc, sA, nullptr, sB, nullptr);
  const int tid = threadIdx.x, wave = tid>>6, lane = tid&63;
  const int l15 = lane&15, l4 = lane>>4;
  const int wr = (wave>>1)*64, wc = (wave&1)*64;
  #pragma unroll
  for (int mi = 0; mi < 4; ++mi) {
    #pragma unroll
    for (int ni = 0; ni < 4; ++ni) {
      const int j = n0 + wc + ni*16 + l15;
      const float bj = bup[j];
      #pragma unroll
      for (int r = 0; r < 4; ++r) {
        const int n = m0 + wr + mi*16 + l4*4 + r;
        const float c = acc[mi][ni][r] + bj;
        const float ge = 0.5f*c*(1.f + erff(c*0.70710678118654752f));
        v3[(size_t)n*9216 + j] = f2bf(ge);
      }
    }
  }
}

// ---------------- out init: out = z1 + b_down -----------------------------------------------
__global__ __launch_bounds__(256) void k_oinit(
    const float* __restrict__ z1, const float* __restrict__ bdn, float* __restrict__ out)
{
  const int i = blockIdx.x*256 + threadIdx.x;      // float4 index; 768%4==0 so no row wrap
  const f32x4 z = *(const f32x4*)(z1 + (size_t)i*4);
  const int d = (i*4) % 768;
  f32x4 o;
  #pragma unroll
  for (int j = 0; j < 4; ++j) o[j] = z[j] + bdn[d+j];
  *(f32x4*)(out + (size_t)i*4) = o;
}

// ---------------- MLP down, split-K=4, atomic accumulate into out (pre-init z1+b) -----------
__global__ __launch_bounds__(256) void k_down(
    const ushort* __restrict__ v3, const ushort* __restrict__ wdnT,
    float* __restrict__ out)
{
  __shared__ char sA[16384], sB[16384];
  const int m0 = blockIdx.x*128, n0 = blockIdx.y*128;
  const int kz = blockIdx.z;               // K chunk: 2304 elements = 4608 bytes
  f32x4 acc[4][4] = {};
  gemm_core<false,64>((const char*)v3 + kz*4608, nullptr, (const char*)wdnT + kz*4608, nullptr,
                      2304, 18432, 18432, m0, n0, acc, sA, nullptr, sB, nullptr);
  const int tid = threadIdx.x, wave = tid>>6, lane = tid&63;
  const int l15 = lane&15, l4 = lane>>4;
  const int wr = (wave>>1)*64, wc = (wave&1)*64;
  #pragma unroll
  for (int mi = 0; mi < 4; ++mi) {
    #pragma unroll
    for (int ni = 0; ni < 4; ++ni) {
      const int d = n0 + wc + ni*16 + l15;
      #pragma unroll
      for (int r = 0; r < 4; ++r) {
        const int n = m0 + wr + mi*16 + l4*4 + r;
        unsafeAtomicAdd(&out[(size_t)n*768 + d], acc[mi][ni][r]);
      }
    }
  }
}

extern "C" void kernel_launch(void* const* d_in, const int* in_sizes, int n_in,
                              void* d_out, int out_size, void* d_ws, size_t ws_size,
                              hipStream_t stream) {
  const float* x   = (const float*)d_in[0];
  const int*   am  = (const int*)d_in[1];
  const float* WQ  = (const float*)d_in[2];
  const float* WK  = (const float*)d_in[3];
  const float* WV  = (const float*)d_in[4];
  const float* g1  = (const float*)d_in[5];
  const float* b1  = (const float*)d_in[6];
  const float* g2  = (const float*)d_in[7];
  const float* b2  = (const float*)d_in[8];
  const float* WO  = (const float*)d_in[9];
  const float* Wup = (const float*)d_in[10];
  const float* bup = (const float*)d_in[11];
  const float* Wdn = (const float*)d_in[12];
  const float* bdn = (const float*)d_in[13];
  float* out = (float*)d_out;

  char* w = (char*)d_ws;
  // weight conversions (persistent through their consumers)
  ushort* wqh  = (ushort*)(w + 0);
  ushort* wql  = (ushort*)(w + 1179648);
  ushort* wkh  = (ushort*)(w + 2359296);
  ushort* wkl  = (ushort*)(w + 3538944);
  ushort* wvb  = (ushort*)(w + 4718592);
  ushort* wob  = (ushort*)(w + 5898240);
  ushort* wupT = (ushort*)(w + 7077888);    // [9216][768] bf16
  ushort* wdnT = (ushort*)(w + 21233664);   // [768][9216] bf16
  float*  z1   = (float*) (w + 35389440);   // [4096][768] fp32
  ushort* v1h  = (ushort*)(w + 47972352);   // [4096][768] bf16
  char*  pool  = w + 54263808;              // 75.5MB pool (attn-phase bufs, then v3)
  ushort* uh   = (ushort*)(pool + 0);
  ushort* ul   = (ushort*)(pool + 6291456);
  ushort* Qh_  = (ushort*)(pool + 12582912);
  ushort* Ql_  = (ushort*)(pool + 18874368);
  ushort* Kh_  = (ushort*)(pool + 25165824);
  ushort* Kl_  = (ushort*)(pool + 31457280);
  ushort* Vt_  = (ushort*)(pool + 37748736);
  ushort* oc   = (ushort*)(pool + 44040192);
  float* Onum  = (float*)(pool + 0);        // overlays dead uh/ul during attn phase (12.58MB)
  float* Oden  = (float*)(pool + 50331648); // after oc (192KB)
  ushort* v3   = (ushort*)(pool + 0);       // overlays whole pool in MLP phase
  const size_t NEED = 54263808u + 75497472u;
  if (ws_size < NEED) return;               // fail cleanly rather than corrupt

  k_prep<<<2304, 256, 0, stream>>>(WQ, WK, WV, WO, wqh, wql, wkh, wkl, wvb, wob);
  k_transpose<<<dim3(288, 24), 256, 0, stream>>>(Wup, wupT, 768, 9216);
  k_transpose<<<dim3(24, 288), 256, 0, stream>>>(Wdn, wdnT, 9216, 768);
  k_ln<<<4096, 256, 0, stream>>>(x, g1, b1, uh, ul);
  k_qkv<<<dim3(32, 6, 3), 256, 0, stream>>>(uh, ul, wqh, wql, wkh, wkl, wvb,
                                            Qh_, Ql_, Kh_, Kl_, Vt_);
  // attn partials (zero-init after k_qkv has consumed uh/ul, which Onum overlays)
  hipMemsetAsync(Onum, 0, 12582912, stream);
  hipMemsetAsync(Oden, 0, 196608, stream);
  k_attn<<<dim3(80, 24), 256, 0, stream>>>(Qh_, Ql_, Kh_, Kl_, Vt_, am, Onum, Oden);
  k_norm<<<3072, 256, 0, stream>>>(Onum, Oden, oc);
  // z1 = x, then W_O GEMM atomically accumulates (split-K=2, 384 blocks)
  hipMemcpyAsync(z1, x, 12582912, hipMemcpyDeviceToDevice, stream);
  k_wo<<<dim3(32, 6, 2), 256, 0, stream>>>(oc, wob, z1);
  k_ln<<<4096, 256, 0, stream>>>(z1, g2, b2, v1h, nullptr);
  k_up<<<dim3(32, 72), 256, 0, stream>>>(v1h, wupT, bup, v3);
  // out = z1 + b_down, then MLP-down atomically accumulates (split-K=4, 768 blocks)
  k_oinit<<<3072, 256, 0, stream>>>(z1, bdn, out);
  k_down<<<dim3(32, 6, 4), 256, 0, stream>>>(v3, wdnT, out);
}